// Round 1
// 343.004 us; speedup vs baseline: 1.1596x; 1.1596x over previous
//
#include <hip/hip_runtime.h>

#define EDIM 10
#define TDIM 50
#define BATCH 65536
#define RPW   32    // rows per wave (lane L<32: half0 of row L; lane L>=32: half1 of row L-32)
#define RPB   128   // 4 waves/block -> grid 512, 8 waves/CU (grid-limited, same as before)

// LDS collapsed-weight layout (floats, 8-wide padded groups for b128 alignment):
//   WA[((g*10+k)*2 + h)*8 + j] = A_g[k][h*5+j]   (A_g = Wi_g @ Ws_g)   g: 0=r,1=z,2=h
//   WB[((g*10+k)*2 + h)*8 + j] = B_g[k][h*5+j]   (B_g = Wh_g @ Ws_g)
//   WBI[(g*2+h)*8 + j]         = bias_g[h*5+j]   (bias_g = bi_g @ Ws_g + bs_g)

__device__ __forceinline__ float fast_sigmoid(float x) {
    float e = __expf(-x);
    return __builtin_amdgcn_rcpf(1.0f + e);
}
__device__ __forceinline__ float fast_tanh(float x) {
    float e = __expf(2.0f * x);
    return 1.0f - 2.0f * __builtin_amdgcn_rcpf(e + 1.0f);
}
// partner-lane exchange (lane ^ 32) — wave-synchronous, no barrier needed
__device__ __forceinline__ float lane_xchg(int pidx, float v) {
    return __int_as_float(__builtin_amdgcn_ds_bpermute(pidx, __float_as_int(v)));
}

__global__ __launch_bounds__(256, 2) void augru_main(
    const float* __restrict__ x_all, const float* __restrict__ a_all,
    const float* __restrict__ h0,
    const float* __restrict__ Wi_r, const float* __restrict__ bi_r,
    const float* __restrict__ Wh_r, const float* __restrict__ Ws_r, const float* __restrict__ bs_r,
    const float* __restrict__ Wi_z, const float* __restrict__ bi_z,
    const float* __restrict__ Wh_z, const float* __restrict__ Ws_z, const float* __restrict__ bs_z,
    const float* __restrict__ Wi_h, const float* __restrict__ bi_h,
    const float* __restrict__ Wh_h, const float* __restrict__ Wt_h, const float* __restrict__ bt_h,
    float* __restrict__ out)
{
    __shared__ __align__(16) float WA[480];
    __shared__ __align__(16) float WB[480];
    __shared__ __align__(16) float WBI[48];

    // ---- preamble: collapse weights into the half-split LDS layout ----
    for (int s = threadIdx.x; s < 630; s += 256) {
        int g, kind, k, e;
        if (s < 30)       { kind = 0; g = s / 10;            k = 0;               e = s % 10; }
        else if (s < 330) { kind = 1; int q = s - 30;  g = q / 100; k = (q % 100) / 10; e = q % 10; }
        else              { kind = 2; int q = s - 330; g = q / 100; k = (q % 100) / 10; e = q % 10; }
        const float* Wi = (g == 0) ? Wi_r : (g == 1) ? Wi_z : Wi_h;
        const float* Wh = (g == 0) ? Wh_r : (g == 1) ? Wh_z : Wh_h;
        const float* Ws = (g == 0) ? Ws_r : (g == 1) ? Ws_z : Wt_h;
        const float* bi = (g == 0) ? bi_r : (g == 1) ? bi_z : bi_h;
        const float* bs = (g == 0) ? bs_r : (g == 1) ? bs_z : bt_h;
        float v = 0.0f;
        if (kind == 0) {
            v = bs[e];
            #pragma unroll
            for (int j2 = 0; j2 < 10; j2++) v += bi[j2] * Ws[j2 * 10 + e];
        } else {
            const float* M = (kind == 1) ? Wi : Wh;
            #pragma unroll
            for (int j2 = 0; j2 < 10; j2++) v += M[k * 10 + j2] * Ws[j2 * 10 + e];
        }
        int hh = e / 5, j = e % 5;
        if (kind == 0)      WBI[(g * 2 + hh) * 8 + j] = v;
        else if (kind == 1) WA[((g * 10 + k) * 2 + hh) * 8 + j] = v;
        else                WB[((g * 10 + k) * 2 + hh) * 8 + j] = v;
    }
    __syncthreads();   // the ONLY barrier in the kernel

    const int lane = threadIdx.x & 63;
    const int wv   = threadIdx.x >> 6;
    const int half = lane >> 5;          // 0: cols 0..4, 1: cols 5..9
    const int rl   = lane & 31;
    const int row  = blockIdx.x * RPB + wv * RPW + rl;
    const int pidx = (lane ^ 32) << 2;   // ds_bpermute byte index of partner lane

    // ---- per-lane VGPR cache of the recurrence-path B matrices ----
    // wbO[g][k5][j]: weight pairing with OWN  h/hz slot k5 (global k = half*5+k5)
    // wbP[g][k5][j]: weight pairing with PARTNER slot k5   (global k = (1-half)*5+k5)
    // Own/partner k-order is baked in here, so the hot loop has zero selects.
    float wbO[3][5][5], wbP[3][5][5];
    #pragma unroll
    for (int g = 0; g < 3; g++)
        #pragma unroll
        for (int k5 = 0; k5 < 5; k5++)
            #pragma unroll
            for (int j = 0; j < 5; j++) {
                wbO[g][k5][j] = WB[((g * 10 + half * 5 + k5) * 2 + half) * 8 + j];
                wbP[g][k5][j] = WB[((g * 10 + (1 - half) * 5 + k5) * 2 + half) * 8 + j];
            }

    const float2* xp2 = (const float2*)(x_all + (size_t)row * (TDIM * EDIM));
    const float*  arp = a_all + (size_t)row * (TDIM * EDIM) + half * 5;
    float* orow = out + (size_t)row * EDIM + half * 5;

    float h[5], ph[5];
    #pragma unroll
    for (int j = 0; j < 5; j++) h[j]  = h0[half * 5 + j];
    #pragma unroll
    for (int j = 0; j < 5; j++) ph[j] = h0[(1 - half) * 5 + j];   // partner init straight from h0

    float2 xc[5]; float ac[5];
    #pragma unroll
    for (int i = 0; i < 5; i++) xc[i] = xp2[i];
    #pragma unroll
    for (int j = 0; j < 5; j++) ac[j] = arp[j];

    // laundered LDS offset: blocks LICM from hoisting the 165 loop-invariant
    // A/bias LDS loads into registers (would blow the VGPR budget). Same
    // rationale as the proven FENCEW trick in earlier rounds.
    int wofs = 0;

    #pragma unroll 1
    for (int t = 0; t < TDIM; t++) {
        asm volatile("" : "+v"(wofs));
        const float* wa  = (const float*)WA  + half * 8 + wofs;
        const float* wbi = (const float*)WBI + half * 8 + wofs;

        // branchless 1-step-lookahead prefetch (clamped)
        int tn = (t < TDIM - 1) ? (t + 1) : t;
        float2 xn[5]; float an[5];
        #pragma unroll
        for (int i = 0; i < 5; i++) xn[i] = xp2[tn * 5 + i];
        #pragma unroll
        for (int j = 0; j < 5; j++) an[j] = arp[tn * 10 + j];

        // ---- r,z: bias + x@A (streamed weights) + h@B (cached weights) ----
        float ur[5], uz[5];
        {
            float4 b4r = *(const float4*)(wbi + 0);
            float4 b4z = *(const float4*)(wbi + 16);
            ur[0] = b4r.x; ur[1] = b4r.y; ur[2] = b4r.z; ur[3] = b4r.w; ur[4] = wbi[4];
            uz[0] = b4z.x; uz[1] = b4z.y; uz[2] = b4z.z; uz[3] = b4z.w; uz[4] = wbi[20];
        }
        #pragma unroll
        for (int k = 0; k < 10; k++) {
            float xk = (k & 1) ? xc[k >> 1].y : xc[k >> 1].x;
            float4 w4 = *(const float4*)(wa + k * 16);
            float  w1 = wa[k * 16 + 4];
            ur[0] = fmaf(xk, w4.x, ur[0]); ur[1] = fmaf(xk, w4.y, ur[1]);
            ur[2] = fmaf(xk, w4.z, ur[2]); ur[3] = fmaf(xk, w4.w, ur[3]);
            ur[4] = fmaf(xk, w1,   ur[4]);
        }
        #pragma unroll
        for (int k = 0; k < 10; k++) {
            float xk = (k & 1) ? xc[k >> 1].y : xc[k >> 1].x;
            float4 w4 = *(const float4*)(wa + 160 + k * 16);
            float  w1 = wa[160 + k * 16 + 4];
            uz[0] = fmaf(xk, w4.x, uz[0]); uz[1] = fmaf(xk, w4.y, uz[1]);
            uz[2] = fmaf(xk, w4.z, uz[2]); uz[3] = fmaf(xk, w4.w, uz[3]);
            uz[4] = fmaf(xk, w1,   uz[4]);
        }
        #pragma unroll
        for (int k5 = 0; k5 < 5; k5++)
            #pragma unroll
            for (int j = 0; j < 5; j++) {
                ur[j] = fmaf(h[k5], wbO[0][k5][j], ur[j]);
                uz[j] = fmaf(h[k5], wbO[1][k5][j], uz[j]);
            }
        #pragma unroll
        for (int k5 = 0; k5 < 5; k5++)
            #pragma unroll
            for (int j = 0; j < 5; j++) {
                ur[j] = fmaf(ph[k5], wbP[0][k5][j], ur[j]);
                uz[j] = fmaf(ph[k5], wbP[1][k5][j], uz[j]);
            }

        // ---- z, hz; exchange hz with partner (latency hidden by x@A_h below) ----
        float z5[5], hzo[5], phz[5];
        #pragma unroll
        for (int j = 0; j < 5; j++) { z5[j] = fast_sigmoid(uz[j]); hzo[j] = h[j] * z5[j]; }
        #pragma unroll
        for (int j = 0; j < 5; j++) phz[j] = lane_xchg(pidx, hzo[j]);

        // ---- h-candidate: bias + x@A_h + hz@B_h (own part first, partner after) ----
        float uh[5];
        {
            float4 b4h = *(const float4*)(wbi + 32);
            uh[0] = b4h.x; uh[1] = b4h.y; uh[2] = b4h.z; uh[3] = b4h.w; uh[4] = wbi[36];
        }
        #pragma unroll
        for (int k = 0; k < 10; k++) {
            float xk = (k & 1) ? xc[k >> 1].y : xc[k >> 1].x;
            float4 w4 = *(const float4*)(wa + 320 + k * 16);
            float  w1 = wa[320 + k * 16 + 4];
            uh[0] = fmaf(xk, w4.x, uh[0]); uh[1] = fmaf(xk, w4.y, uh[1]);
            uh[2] = fmaf(xk, w4.z, uh[2]); uh[3] = fmaf(xk, w4.w, uh[3]);
            uh[4] = fmaf(xk, w1,   uh[4]);
        }
        #pragma unroll
        for (int k5 = 0; k5 < 5; k5++)
            #pragma unroll
            for (int j = 0; j < 5; j++) uh[j] = fmaf(hzo[k5], wbO[2][k5][j], uh[j]);
        #pragma unroll
        for (int k5 = 0; k5 < 5; k5++)
            #pragma unroll
            for (int j = 0; j < 5; j++) uh[j] = fmaf(phz[k5], wbP[2][k5][j], uh[j]);

        // ---- gate + update ----
        #pragma unroll
        for (int j = 0; j < 5; j++) {
            float r  = fast_sigmoid(ur[j]);
            float hc = fast_tanh(uh[j]);
            float Ra = ac[j] * r;
            h[j] = fmaf(Ra, hc - h[j], h[j]);
        }

        // exchange updated h for next iteration (completes during next A-phase)
        #pragma unroll
        for (int j = 0; j < 5; j++) ph[j] = lane_xchg(pidx, h[j]);

        #pragma unroll
        for (int i = 0; i < 5; i++) xc[i] = xn[i];
        #pragma unroll
        for (int j = 0; j < 5; j++) ac[j] = an[j];
    }

    // own 5 columns out (2.6 MB total -> coalescing irrelevant)
    #pragma unroll
    for (int j = 0; j < 5; j++) orow[j] = h[j];
}

extern "C" void kernel_launch(void* const* d_in, const int* in_sizes, int n_in,
                              void* d_out, int out_size, void* d_ws, size_t ws_size,
                              hipStream_t stream) {
    augru_main<<<BATCH / RPB, 256, 0, stream>>>(
        (const float*)d_in[0],  (const float*)d_in[1],  (const float*)d_in[2],
        (const float*)d_in[3],  (const float*)d_in[4],  (const float*)d_in[5],
        (const float*)d_in[6],  (const float*)d_in[7],
        (const float*)d_in[8],  (const float*)d_in[9],  (const float*)d_in[10],
        (const float*)d_in[11], (const float*)d_in[12],
        (const float*)d_in[13], (const float*)d_in[14], (const float*)d_in[15],
        (const float*)d_in[16], (const float*)d_in[17],
        (float*)d_out);
}